// Round 7
// baseline (329.434 us; speedup 1.0000x reference)
//
#include <hip/hip_runtime.h>

#define NTOT 196608
#define BAGS 4096
#define H 230
#define H3 690
#define NC 53

// One-instruction cross-lane reduce step: ds_swizzle BitMode xor patterns.
// (xor<<10)|(or<<5)|and, and=0x1F -> operates WITHIN each 32-lane half,
// which is exactly what the half-wave row layout needs. HW-verified in R5.
#define SWZ_ADD(v, pat) \
    ((v) + __int_as_float(__builtin_amdgcn_ds_swizzle(__float_as_int(v), (pat))))

// tanh(x) = 1 - 2/(exp(2x)+1), v_rcp instead of precise division.
__device__ __forceinline__ float fast_tanh(float x) {
    float e = __expf(2.f * x);
    float r = __builtin_amdgcn_rcpf(e + 1.f);
    return fmaf(-2.f, r, 1.f);
}

// ---------------------------------------------------------------------------
// Kernel 0: per-class table, now PACKED as float4 per class:
// cls4[c] = { logit_const_k0, logit_const_k1, vsm0, vsm1 }  (one load/row).
// ---------------------------------------------------------------------------
__global__ void class_table_kernel(const float* __restrict__ rel_emb0,
                                   const float* __restrict__ rel_emb1,
                                   const float* __restrict__ att_w0,
                                   const float* __restrict__ att_w1,
                                   const float* __restrict__ w_s,
                                   const float* __restrict__ b_s,
                                   const int* __restrict__ relation_levels,
                                   float* __restrict__ cls)
{
    int c = blockIdx.x;
    int lane = threadIdx.x;  // 64 threads
    int l0 = relation_levels[c * 2 + 0];
    int l1 = relation_levels[c * 2 + 1];
    float a00 = 0.f, a01 = 0.f, a10 = 0.f, a11 = 0.f;
    for (int j = lane; j < H; j += 64) {
        float t0 = fast_tanh(rel_emb0[l0 * H + j]);
        float t1 = fast_tanh(rel_emb1[l1 * H + j]);
        a00 += w_s[0 * H3 + H + j] * t0;
        a01 += w_s[0 * H3 + 2 * H + j] * t1;
        a10 += w_s[1 * H3 + H + j] * t0;
        a11 += w_s[1 * H3 + 2 * H + j] * t1;
    }
    for (int m = 32; m; m >>= 1) {
        a00 += __shfl_xor(a00, m);
        a01 += __shfl_xor(a01, m);
        a10 += __shfl_xor(a10, m);
        a11 += __shfl_xor(a11, m);
    }
    if (lane == 0) {
        float v0 = att_w0[l0], v1 = att_w1[l1];
        float mx = fmaxf(v0, v1);
        float e0 = __expf(v0 - mx), e1 = __expf(v1 - mx);
        float rz = __builtin_amdgcn_rcpf(e0 + e1);
        float4 v;
        v.x = a00 + a01 + b_s[0];
        v.y = a10 + a11 + b_s[1];
        v.z = e0 * rz;
        v.w = e1 * rz;
        ((float4*)cls)[c] = v;
    }
}

// ---------------------------------------------------------------------------
// Kernel 1: one block per bag, single pass over x, HALF-WAVE PAIRED ROWS.
// R0-R6 evidence: bag stuck at ~102-105us across all high-occupancy variants;
// prefetch/scalarization neutral => exposed latency is the per-row 64-lane
// reduce (12 DS ops, ~240cy chain) x 12 serial trips. This layout puts row A
// in lanes 0-31, row B in lanes 32-63 (8 cols/lane via 4x float2, always
// 8B-aligned): reduce = 5 ds_swizzle steps within a half, serving BOTH rows
// -> DS ops/row 12->5, trips/wave 12->6. Unified masked loop (no fallback).
// Registers ~60 -> (256,8) max occupancy. LDS 18.3KB < 20KB/block.
// Tripwires: VGPR<=64, WRITE_SIZE ~1MB (else scratch relapse).
// ---------------------------------------------------------------------------
__global__ __launch_bounds__(256, 8) void bag_kernel(
    const float* __restrict__ x,
    const float* __restrict__ w_s,
    const float* __restrict__ disc,
    const float* __restrict__ bias,
    const int* __restrict__ label_index,
    const int* __restrict__ scope,
    const float* __restrict__ cls,
    float* __restrict__ out)
{
    __shared__ __align__(16) float part[4][2][2][256];  // [wave][half][ch][col] 16KB
    __shared__ float zs[4][4];                          // per-wave z0,z1,sv0,sv1
    __shared__ __align__(16) float t01[464];            // tower (t0 | t1)

    int b = blockIdx.x;
    int tid = threadIdx.x;
    int wave = tid >> 6;
    int lane = tid & 63;
    int half = lane >> 5;      // 0: row A, 1: row B
    int hl   = lane & 31;      // lane within half; owns cols 8*hl .. 8*hl+7

    int start = __builtin_amdgcn_readfirstlane(scope[b]);
    int cnt   = __builtin_amdgcn_readfirstlane(scope[b + 1]) - start;

    // float2 indices for this lane's 8 columns, clamped in-row (cols >= H get
    // garbage values but zero weights; never stored to meaningful outputs).
    int j0 = 8 * hl;
    int i0 = (j0 >> 1);            // 4*hl
    int i1 = i0 + 1, i2 = i0 + 2, i3 = i0 + 3;
    if (i0 > 114) i0 = 114;
    if (i1 > 114) i1 = 114;
    if (i2 > 114) i2 = 114;
    if (i3 > 114) i3 = 114;

    // Weight slices for this lane's columns (zero past H).
    float w0r[8], w1r[8];
#pragma unroll
    for (int k = 0; k < 8; ++k) {
        int j = j0 + k;
        w0r[k] = (j < H) ? w_s[j] : 0.f;
        w1r[k] = (j < H) ? w_s[H3 + j] : 0.f;
    }

    float acc0[8], acc1[8];
#pragma unroll
    for (int k = 0; k < 8; ++k) { acc0[k] = 0.f; acc1[k] = 0.f; }
    float z0 = 0.f, z1 = 0.f, sv0 = 0.f, sv1 = 0.f;

    const float4* cls4 = (const float4*)cls;

    // ---- Main loop: trip m handles rows (wave+8m) [half 0] and (wave+8m+4)
    // [half 1]. Invalid high-half rows contribute e=0.
    for (int m = 0; wave + 8 * m < cnt; ++m) {
        int rMine = wave + 8 * m + 4 * half;
        int valid = (rMine < cnt);
        int rq = valid ? rMine : (cnt - 1);

        const float2* rp = (const float2*)(x + (long long)(start + rq) * H);
        float2 v0 = rp[i0], v1 = rp[i1], v2 = rp[i2], v3 = rp[i3];
        int c = label_index[start + rq];       // 2 distinct addrs/wave, L1-hot
        float4 cv = cls4[c];                   // k0,k1,vsm0,vsm1

        float r[8] = { v0.x, v0.y, v1.x, v1.y, v2.x, v2.y, v3.x, v3.y };
        float d0 = 0.f, d1 = 0.f;
#pragma unroll
        for (int k = 0; k < 8; ++k) {
            float th = fast_tanh(r[k]);
            d0 += w0r[k] * th;
            d1 += w1r[k] * th;
        }
        // 5-step reduce within the 32-lane half (both rows simultaneously).
        d0 = SWZ_ADD(d0, 0x041F); d1 = SWZ_ADD(d1, 0x041F);   // xor 1
        d0 = SWZ_ADD(d0, 0x081F); d1 = SWZ_ADD(d1, 0x081F);   // xor 2
        d0 = SWZ_ADD(d0, 0x101F); d1 = SWZ_ADD(d1, 0x101F);   // xor 4
        d0 = SWZ_ADD(d0, 0x201F); d1 = SWZ_ADD(d1, 0x201F);   // xor 8
        d0 = SWZ_ADD(d0, 0x401F); d1 = SWZ_ADD(d1, 0x401F);   // xor 16

        float e0 = __expf(d0 + cv.x);
        float e1 = __expf(d1 + cv.y);
        e0 = valid ? e0 : 0.f;                 // select, not multiply (inf*0)
        e1 = valid ? e1 : 0.f;
        z0 += e0; z1 += e1;
        sv0 += valid ? cv.z : 0.f;
        sv1 += valid ? cv.w : 0.f;
#pragma unroll
        for (int k = 0; k < 8; ++k) {
            acc0[k] = fmaf(e0, r[k], acc0[k]);
            acc1[k] = fmaf(e1, r[k], acc1[k]);
        }
    }

    // ---- Merge z/sv across halves, then stash per wave.
    z0  += __shfl_xor(z0, 32);  z1  += __shfl_xor(z1, 32);
    sv0 += __shfl_xor(sv0, 32); sv1 += __shfl_xor(sv1, 32);
    if (lane == 0) {
        zs[wave][0] = z0; zs[wave][1] = z1;
        zs[wave][2] = sv0; zs[wave][3] = sv1;
    }

    // ---- Weighted-sum partials to LDS (float4 stores, 32B/lane).
    {
        float4* p0 = (float4*)&part[wave][half][0][8 * hl];
        float4* p1 = (float4*)&part[wave][half][1][8 * hl];
        p0[0] = make_float4(acc0[0], acc0[1], acc0[2], acc0[3]);
        p0[1] = make_float4(acc0[4], acc0[5], acc0[6], acc0[7]);
        p1[0] = make_float4(acc1[0], acc1[1], acc1[2], acc1[3]);
        p1[1] = make_float4(acc1[4], acc1[5], acc1[6], acc1[7]);
    }
    __syncthreads();

    float zt0 = zs[0][0] + zs[1][0] + zs[2][0] + zs[3][0];
    float zt1 = zs[0][1] + zs[1][1] + zs[2][1] + zs[3][1];
    float st0 = zs[0][2] + zs[1][2] + zs[2][2] + zs[3][2];
    float st1 = zs[0][3] + zs[1][3] + zs[2][3] + zs[3][3];
    float rc  = __builtin_amdgcn_rcpf((float)cnt);
    float s0  = st0 * rc * __builtin_amdgcn_rcpf(zt0);  // layer_att0 / z0
    float s1  = st1 * rc * __builtin_amdgcn_rcpf(zt1);  // layer_att1 / z1

    for (int t = tid; t < 2 * H; t += 256) {
        int ch = (t >= H);
        int c  = t - ch * H;
        float s = part[0][0][ch][c] + part[0][1][ch][c]
                + part[1][0][ch][c] + part[1][1][ch][c]
                + part[2][0][ch][c] + part[2][1][ch][c]
                + part[3][0][ch][c] + part[3][1][ch][c];
        t01[t] = s * (ch ? s1 : s0);
    }
    __syncthreads();

    // ---- Output projection, float4 both sides. 4 threads per class.
    int q = tid & 3;
    int c = tid >> 2;
    if (c < NC) {
        const float4* drow4 = (const float4*)(disc + c * (2 * H)); // 115 float4
        const float4* t4 = (const float4*)t01;
        float acc = 0.f;
        for (int k = q; k < 115; k += 4) {
            float4 dv = drow4[k];
            float4 tv = t4[k];
            acc += dv.x * tv.x + dv.y * tv.y + dv.z * tv.z + dv.w * tv.w;
        }
        acc += __shfl_down(acc, 2, 4);
        acc += __shfl_down(acc, 1, 4);
        if (q == 0) out[b * NC + c] = acc + bias[c];
    }
}

extern "C" void kernel_launch(void* const* d_in, const int* in_sizes, int n_in,
                              void* d_out, int out_size, void* d_ws, size_t ws_size,
                              hipStream_t stream) {
    const float* x               = (const float*)d_in[0];
    const float* rel_emb0        = (const float*)d_in[1];
    const float* rel_emb1        = (const float*)d_in[2];
    const float* att_w0          = (const float*)d_in[3];
    const float* att_w1          = (const float*)d_in[4];
    const float* w_s             = (const float*)d_in[5];
    const float* b_s             = (const float*)d_in[6];
    const float* disc            = (const float*)d_in[7];
    const float* bias            = (const float*)d_in[8];
    const int*   label_index     = (const int*)d_in[9];
    const int*   relation_levels = (const int*)d_in[10];
    const int*   scope           = (const int*)d_in[11];
    float* out = (float*)d_out;
    float* cls = (float*)d_ws;   // NC float4s

    class_table_kernel<<<NC, 64, 0, stream>>>(rel_emb0, rel_emb1, att_w0, att_w1,
                                              w_s, b_s, relation_levels, cls);
    bag_kernel<<<BAGS, 256, 0, stream>>>(x, w_s, disc, bias, label_index, scope,
                                         cls, out);
}